// Round 13
// baseline (47.321 us; speedup 1.0000x reference)
//
#include <hip/hip_runtime.h>
#include <hip/hip_bf16.h>

// Problem: B=16, C=256, H=64, W=64, OUT=256
//   scale[b,c] = mean(context[b,c,:,:])
//   out[b,o,hw] = sum_c w1[o,c]*scale[b,c]*x[b,c,hw] + b1[o]
// R13: barrier-free gemm. Key insight: the 32x32 MFMA B-fragment
//   (col=lane&31, k=(lane>>5)*8+e) makes DIRECT global B-loads perfectly
//   coalesced (2 x 128B fully-used segments per instruction) -- no LDS, no
//   barriers, no bf16-pack->LDS roundtrip, no redundant LDS re-reads. R1/R6's
//   no-LDS attempts failed only because 16-lane fragments use 64B segments.
//   1024 blocks (XCD-swizzled), 128x128 tile per block, wave = 128x32,
//   B prefetched 1 K-step ahead in regs, A (L2-resident w2f) loaded at use.
//   16 waves/CU of pure dataflow; compiler schedules freely (no barriers).

typedef __attribute__((ext_vector_type(8))) short short8;
typedef __attribute__((ext_vector_type(16))) float f32x16;
typedef __attribute__((ext_vector_type(4))) unsigned int u32x4;

static __device__ __forceinline__ unsigned int bfbits(float f) {
    unsigned int u = __float_as_uint(f);
    return u + 0x7FFFu + ((u >> 16) & 1u);  // bf16 (RTNE) in bits 16..31
}

static __device__ __forceinline__ unsigned int pkbf(float lo, float hi) {
#if __has_builtin(__builtin_amdgcn_perm)
    return __builtin_amdgcn_perm(bfbits(hi), bfbits(lo), 0x07060302u);
#else
    return (bfbits(lo) >> 16) | (bfbits(hi) & 0xffff0000u);
#endif
}

// ---------------- Kernel 1: scale[b*256+c] = mean over 4096 elems ----------
__global__ __launch_bounds__(256) void scale_kernel(const float* __restrict__ ctx,
                                                    float* __restrict__ scale) {
    const int bc = blockIdx.x;              // 0..4095
    const float4* p = (const float4*)(ctx + (size_t)bc * 4096);
    const int t = threadIdx.x;
    float s = 0.f;
#pragma unroll
    for (int k = 0; k < 4; k++) {
        float4 v = p[t + k * 256];
        s += v.x + v.y + v.z + v.w;
    }
#pragma unroll
    for (int off = 32; off > 0; off >>= 1) s += __shfl_down(s, off);
    __shared__ float ws[4];
    if ((t & 63) == 0) ws[t >> 6] = s;
    __syncthreads();
    if (t == 0) scale[bc] = (ws[0] + ws[1] + ws[2] + ws[3]) * (1.0f / 4096.0f);
}

// ---------------- Kernel 2: w2f = scale-folded w1, 32x32x16-fragment layout -
// w2f (ushort): [((b*16+ks)*8 + mt)*64 + lane]*8 + e
//   = bf16( w1[mt*32+(lane&31)][ks*16+(lane>>5)*8+e] * scale[b][same c] )
__global__ __launch_bounds__(256) void w2f_kernel(const float* __restrict__ w1,
                                                  const float* __restrict__ scale,
                                                  unsigned short* __restrict__ w2f) {
    const int gt = blockIdx.x * 256 + threadIdx.x;  // 0..131071
    const int l = gt & 63;
    const int mt = (gt >> 6) & 7;
    const int ks = (gt >> 9) & 15;
    const int b = gt >> 13;
    const int row = mt * 32 + (l & 31);
    const int c0 = ks * 16 + (l >> 5) * 8;

    const float* wr = w1 + row * 256 + c0;
    const float* sc = scale + b * 256 + c0;
    float4 wv0 = *(const float4*)(wr);
    float4 wv1 = *(const float4*)(wr + 4);
    float4 sv0 = *(const float4*)(sc);
    float4 sv1 = *(const float4*)(sc + 4);

    u32x4 pv;
    pv[0] = pkbf(wv0.x * sv0.x, wv0.y * sv0.y);
    pv[1] = pkbf(wv0.z * sv0.z, wv0.w * sv0.w);
    pv[2] = pkbf(wv1.x * sv1.x, wv1.y * sv1.y);
    pv[3] = pkbf(wv1.z * sv1.z, wv1.w * sv1.w);
    *(u32x4*)(w2f + (size_t)gt * 8) = pv;   // coalesced 16B store
}

// ---------------- Kernel 3: barrier-free per-batch GEMM -------------------
// 1024 blocks, XCD swizzle: work = (bid&7)*128 + bid>>3 (bijective).
// b = work>>6, row-half rh = (work>>5)&1, col-group cg = work&31.
// Wave w: rows rh*128 + mt*32 (mt=0..3), cols cg*128 + w*32.
// Per K16 step: 4 A-frags (16B coalesced, L2 w2f) + 8 B-dwords (128B-segment
// coalesced, L3-warm x) + pkbf + 4 MFMA. B prefetched 1 step ahead.
__global__ __launch_bounds__(256, 4) void gemm_kernel(const float* __restrict__ x,
                                                      const unsigned short* __restrict__ w2f,
                                                      const float* __restrict__ b1,
                                                      float* __restrict__ out) {
    const int bid = blockIdx.x;        // 1024
    const int work = (bid & 7) * 128 + (bid >> 3);
    const int b = work >> 6;           // batch (2 per XCD)
    const int rh = (work >> 5) & 1;    // row half
    const int cg = work & 31;          // col group
    const int tid = threadIdx.x;
    const int w = tid >> 6;
    const int lane = tid & 63;
    const int l31 = lane & 31;
    const int lh = lane >> 5;          // 0/1
    const int cw = cg * 128 + w * 32;  // wave's 32-col base

    const unsigned short* Af = w2f + (size_t)b * 65536;   // [16ks][8mt][64l][8]
    const float* Xcol = x + (size_t)b * (256 * 4096) + cw + l31;  // per-lane col

    f32x16 acc[4];
#pragma unroll
    for (int mt = 0; mt < 4; mt++) acc[mt] = (f32x16)(0.f);

    float bcur[8], bnxt[8];
#pragma unroll
    for (int e = 0; e < 8; e++) bcur[e] = Xcol[(size_t)(lh * 8 + e) * 4096];

#pragma unroll
    for (int kt = 0; kt < 16; kt++) {
        // next-step B loads first: coalesced, stay in flight under this step
        if (kt < 15) {
#pragma unroll
            for (int e = 0; e < 8; e++)
                bnxt[e] = Xcol[(size_t)((kt + 1) * 16 + lh * 8 + e) * 4096];
        }
        // A fragments: 16B/lane coalesced from L2-resident w2f
        short8 a[4];
#pragma unroll
        for (int mt = 0; mt < 4; mt++)
            a[mt] = *(const short8*)(
                Af + (((size_t)kt * 8 + rh * 4 + mt) * 64 + lane) * 8);
        // pack B to bf16x8
        u32x4 pv;
#pragma unroll
        for (int j = 0; j < 4; j++) pv[j] = pkbf(bcur[2 * j], bcur[2 * j + 1]);
        short8 bfr = __builtin_bit_cast(short8, pv);
#pragma unroll
        for (int mt = 0; mt < 4; mt++)
            acc[mt] = __builtin_amdgcn_mfma_f32_32x32x16_bf16(a[mt], bfr, acc[mt], 0, 0, 0);
#pragma unroll
        for (int e = 0; e < 8; e++) bcur[e] = bnxt[e];
    }

    // ---- epilogue: D (32x32): col = lane&31, row = (r&3) + 8*(r>>2) + 4*lh
    float* outp = out + (size_t)b * 256 * 4096 + cw + l31;
#pragma unroll
    for (int mt = 0; mt < 4; mt++) {
#pragma unroll
        for (int r = 0; r < 16; r++) {
            const int row = rh * 128 + mt * 32 + (r & 3) + 8 * (r >> 2) + 4 * lh;
            outp[(size_t)row * 4096] = acc[mt][r] + b1[row];
        }
    }
}

extern "C" void kernel_launch(void* const* d_in, const int* in_sizes, int n_in,
                              void* d_out, int out_size, void* d_ws, size_t ws_size,
                              hipStream_t stream) {
    const float* x = (const float*)d_in[0];
    const float* context = (const float*)d_in[1];
    const float* w1 = (const float*)d_in[2];
    const float* b1 = (const float*)d_in[3];
    float* out = (float*)d_out;

    float* scale = (float*)d_ws;                                   // 16 KB
    unsigned short* w2f = (unsigned short*)((char*)d_ws + 16384);  // 2 MB

    scale_kernel<<<4096, 256, 0, stream>>>(context, scale);
    w2f_kernel<<<512, 256, 0, stream>>>(w1, scale, w2f);
    gemm_kernel<<<1024, 256, 0, stream>>>(x, w2f, b1, out);
}